// Round 5
// baseline (241.423 us; speedup 1.0000x reference)
//
#include <hip/hip_runtime.h>
#include <hip/hip_bf16.h>
#include <hip/hip_fp8.h>

// Problem constants (fixed shapes: N=M=8192, D=1024)
#define D_K 1024
#define TILE 128
#define ROWB 512     // bytes per fp4 row (1024 elems * 4 bits)

typedef int intx8 __attribute__((ext_vector_type(8)));
typedef float floatx4 __attribute__((ext_vector_type(4)));

// Encode scaled value (target grid = e2m1 {0,.5,1,1.5,2,3,4,6}) -> 4-bit code.
__device__ __forceinline__ unsigned int f2fp4(float v) {
    const float a = fabsf(v);
    unsigned int c = (unsigned int)(a >= 0.25f) + (a >= 0.75f) + (a >= 1.25f)
                   + (a >= 1.75f) + (a >= 2.5f) + (a >= 3.5f) + (a >= 5.0f);
    return c | (v < 0.0f ? 8u : 0u);
}

// Load one 16B fp4 fragment (32 K-elems) DIRECTLY from global/L2.
// fp4 data occupies v[0:3] of the 8-reg MFMA operand; upper half zero.
__device__ __forceinline__ intx8 ld_g16(const unsigned char* p) {
    const int4 d = *(const int4*)p;
    intx8 v;
    v[0] = d.x; v[1] = d.y; v[2] = d.z; v[3] = d.w;
    v[4] = 0; v[5] = 0; v[6] = 0; v[7] = 0;
    return v;
}

// ---------------------------------------------------------------------------
// Kernel 1: per-row normalize q,n -> fp4 e2m1 (pre-scaled x32, compensated by
// MFMA e8m0 scale 2^-5 per side); positive-pair term per row.
// One WAVE per row (4 rows/block): no barriers, butterfly reduce in-wave.
// ---------------------------------------------------------------------------
__global__ __launch_bounds__(256)
void prep_kernel(const float* __restrict__ q, const float* __restrict__ p,
                 const float* __restrict__ ng,
                 unsigned short* __restrict__ qn, unsigned short* __restrict__ nn,
                 float* __restrict__ posp) {
    const int wid = threadIdx.x >> 6, lane = threadIdx.x & 63;
    const int row = blockIdx.x * 4 + wid;
    const size_t base = (size_t)row * D_K;
    const float4* q4 = (const float4*)(q + base);
    const float4* p4 = (const float4*)(p + base);
    const float4* n4 = (const float4*)(ng + base);

    float4 qa[4], na[4];
    float qq = 0.f, pp = 0.f, qp = 0.f, nn2 = 0.f;
#pragma unroll
    for (int j = 0; j < 4; j++) {
        qa[j] = q4[j * 64 + lane];
        float4 pa = p4[j * 64 + lane];
        na[j] = n4[j * 64 + lane];
        qq += qa[j].x*qa[j].x + qa[j].y*qa[j].y + qa[j].z*qa[j].z + qa[j].w*qa[j].w;
        pp += pa.x*pa.x + pa.y*pa.y + pa.z*pa.z + pa.w*pa.w;
        qp += qa[j].x*pa.x + qa[j].y*pa.y + qa[j].z*pa.z + qa[j].w*pa.w;
        nn2 += na[j].x*na[j].x + na[j].y*na[j].y + na[j].z*na[j].z + na[j].w*na[j].w;
    }
#pragma unroll
    for (int off = 1; off < 64; off <<= 1) {
        qq += __shfl_xor(qq, off);
        pp += __shfl_xor(pp, off);
        qp += __shfl_xor(qp, off);
        nn2 += __shfl_xor(nn2, off);
    }
    const float rq = 32.0f / fmaxf(sqrtf(qq), 1e-8f);   // x32 pre-scale folded in
    const float rn = 32.0f / fmaxf(sqrtf(nn2), 1e-8f);

    // row = 512 B = 256 ushorts; ushort j*64+lane packs elems (j*64+lane)*4..+3
    unsigned short* qr = qn + (size_t)row * 256;
    unsigned short* nr = nn + (size_t)row * 256;
#pragma unroll
    for (int j = 0; j < 4; j++) {
        unsigned int w = f2fp4(qa[j].x * rq) | (f2fp4(qa[j].y * rq) << 4)
                       | (f2fp4(qa[j].z * rq) << 8) | (f2fp4(qa[j].w * rq) << 12);
        qr[j * 64 + lane] = (unsigned short)w;
        w = f2fp4(na[j].x * rn) | (f2fp4(na[j].y * rn) << 4)
          | (f2fp4(na[j].z * rn) << 8) | (f2fp4(na[j].w * rn) << 12);
        nr[j * 64 + lane] = (unsigned short)w;
    }

    if (lane == 0) {
        const float rp = 1.0f / fmaxf(sqrtf(pp), 1e-8f);
        const float sim = qp * (rq / 32.0f) * rp;
        const float ap = fmaxf(1.5f - sim, 0.0f);          // clamp_min(-s + (1+m), 0), m=0.5
        const float sp = -ap * (sim - 0.5f);               // -ap*(s - (1-m))
        posp[row] = __expf(sp - 4.0f);                     // shift C=4 (s_pos <= 3.75)
    }
}

// ---------------------------------------------------------------------------
// Kernel 2 (R11): NO-LDS direct-from-L2 GEMM. Ledger of failed schedule
// variants (R7 256²-2ph 50.8, R8 256²-8ph 57.6, R9 128²-dbuf 54.3,
// R10 32x32 50.0 — all vs R0's 45.8): the 2-barrier-per-K-tile LDS
// structure is a plateau whose cost is the barrier drain, and at NT=4 no
// schedule removes it. This kernel removes the REASON for the barrier:
// the whole fp4 problem is 8.4 MB (B-matrix 4.2 MB ~ one XCD L2), so MFMA
// fragments are loaded per-lane directly from global (guide common-mistake
// #7: stage only when data doesn't cache-fit).
//   - zero barriers, zero LDS, zero staging instructions in the hot loop;
//     waves fully independent; compiler pipelines loads across MFMAs freely.
//   - per-lane frag addr: row*512 + kk*64 + quad*16 -> 8 base pointers
//     computed once; all kk offsets are immediate (<= 448).
//   - register reuse preserved: each frag feeds 4 MFMAs; L2 traffic
//     4096 blocks x 256 KB = 1.07 GB -> ~31 us at 34.5 TB/s ceiling.
//   - frag layout per 16x16x128 fp4: lane(quad,r) holds row (base+i*16+r),
//     K-elems [kk*128 + quad*32 .. +32) = bytes kk*64 + quad*16 (identical
//     mapping to the proven R0 LDS reader, minus the swizzle).
// ---------------------------------------------------------------------------
__global__ __launch_bounds__(256, 2)
void gemm_lse_fp4(const unsigned char* __restrict__ A,
                  const unsigned char* __restrict__ B,
                  float* __restrict__ negp) {
    const int tid = threadIdx.x;
    const int wid = tid >> 6;
    const int lane = tid & 63;
    const int tile_m = blockIdx.y * TILE;
    const int tile_n = blockIdx.x * TILE;

    const int wave_m = (wid & 1) * 64;
    const int wave_n = (wid >> 1) * 64;
    const int quad = lane >> 4;
    const int r = lane & 15;

    floatx4 acc[4][4] = {};

    // 8 K-invariant base pointers (per-lane); kk advances by immediate +64.
    const unsigned char* pa[4];
    const unsigned char* pb[4];
#pragma unroll
    for (int i = 0; i < 4; i++) {
        pa[i] = A + (size_t)(tile_m + wave_m + i * 16 + r) * ROWB + quad * 16;
        pb[i] = B + (size_t)(tile_n + wave_n + i * 16 + r) * ROWB + quad * 16;
    }

#pragma unroll
    for (int kk = 0; kk < 8; kk++) {          // 8 K-steps of 128 elems
        intx8 a[4], b[4];
#pragma unroll
        for (int i = 0; i < 4; i++) a[i] = ld_g16(pa[i] + kk * 64);
#pragma unroll
        for (int j = 0; j < 4; j++) b[j] = ld_g16(pb[j] + kk * 64);

#pragma unroll
        for (int i = 0; i < 4; i++)
#pragma unroll
            for (int j = 0; j < 4; j++)
                acc[i][j] = __builtin_amdgcn_mfma_scale_f32_16x16x128_f8f6f4(
                    a[i], b[j], acc[i][j],
                    4, 4,                 // cbsz=4 / blgp=4: A,B fp4 e2m1
                    0, 0x7A7A7A7A,        // scale_a = 122 -> 2^-5
                    0, 0x7A7A7A7A);       // scale_b = 122 -> 2^-5
    }

    // epilogue: circle-loss transform + exp-sum (shift C=4; s_neg <= ~4)
    float lsum = 0.0f;
#pragma unroll
    for (int i = 0; i < 4; i++)
#pragma unroll
        for (int j = 0; j < 4; j++)
#pragma unroll
            for (int el = 0; el < 4; el++) {
                const float s = acc[i][j][el];
                const float an = fmaxf(s + 1.5f, 0.0f);    // clamp_min(s + (1+m), 0)
                const float sn = an * (s + 0.5f);          // an*(s - delta_n), delta_n = -(1-m)
                lsum += __expf(sn - 4.0f);
            }
    for (int off = 32; off > 0; off >>= 1) lsum += __shfl_down(lsum, off);
    __shared__ float red[4];
    if (lane == 0) red[wid] = lsum;
    __syncthreads();
    if (tid == 0)
        negp[blockIdx.y * gridDim.x + blockIdx.x] = red[0] + red[1] + red[2] + red[3];
}

// ---------------------------------------------------------------------------
// Kernel 3: reduce partials, assemble softplus(lse_neg + lse_pos).
// ---------------------------------------------------------------------------
__global__ __launch_bounds__(1024)
void finalize_kernel(const float* __restrict__ negp, int n_neg,
                     const float* __restrict__ posp, int n_pos,
                     float* __restrict__ out) {
    double sn = 0.0, sp = 0.0;
    for (int i = threadIdx.x; i < n_neg; i += 1024) sn += (double)negp[i];
    for (int i = threadIdx.x; i < n_pos; i += 1024) sp += (double)posp[i];
    for (int off = 32; off > 0; off >>= 1) {
        sn += __shfl_down(sn, off);
        sp += __shfl_down(sp, off);
    }
    __shared__ double rn[16], rp[16];
    const int wid = threadIdx.x >> 6, lane = threadIdx.x & 63;
    if (lane == 0) { rn[wid] = sn; rp[wid] = sp; }
    __syncthreads();
    if (threadIdx.x == 0) {
        double NS = 0.0, PS = 0.0;
#pragma unroll
        for (int w = 0; w < 16; w++) { NS += rn[w]; PS += rp[w]; }
        const double x = (4.0 + log(NS)) + (4.0 + log(PS));
        const double spl = (x > 30.0) ? x : log1p(exp(x));
        out[0] = (float)spl;
    }
}

extern "C" void kernel_launch(void* const* d_in, const int* in_sizes, int n_in,
                              void* d_out, int out_size, void* d_ws, size_t ws_size,
                              hipStream_t stream) {
    const float* q = (const float*)d_in[0];
    const float* p = (const float*)d_in[1];
    const float* ng = (const float*)d_in[2];
    // d_in[3] (text_neg_index) is unused in this branch of the reference.

    const int N = in_sizes[3];          // 8192
    const int D = in_sizes[0] / N;      // 1024 (== D_K)
    const int M = in_sizes[2] / D;      // 8192

    char* ws = (char*)d_ws;
    unsigned short* qn = (unsigned short*)ws;                       // N*512 B
    unsigned short* nn = (unsigned short*)(ws + (size_t)N * ROWB);  // M*512 B
    float* negp = (float*)(ws + (size_t)(N + M) * ROWB);
    const int n_neg = (M / TILE) * (N / TILE);
    float* posp = negp + n_neg;

    // N == M for this problem, so one prep pass covers q/p rows and n rows.
    prep_kernel<<<N / 4, 256, 0, stream>>>(q, p, ng, qn, nn, posp);
    gemm_lse_fp4<<<dim3(M / TILE, N / TILE), 256, 0, stream>>>(
        (const unsigned char*)qn, (const unsigned char*)nn, negp);
    finalize_kernel<<<1, 1024, 0, stream>>>(negp, n_neg, posp, N, (float*)d_out);
}